// Round 2
// baseline (8422.826 us; speedup 1.0000x reference)
//
#include <hip/hip_runtime.h>
#include <math.h>

// SPINN forward, fp32, single persistent kernel with device-wide barriers.
// Phases per step: A = GEMM1 + GEMM2a (work-stealing units) | B = cell/logits/argmax
//                  C = th-GEMM (K=256)                      | D = node/stack/X-gather

#define B_ 128
#define CAP 42
#define XW 2048   // X row: [buf_h 0:512 | s1_h 512:1024 | s2_h 1024:1536 | th_old 1536:1792 | th_new 1792:2048]
#define NBLK 256
#define NTHR 256

__device__ __forceinline__ float sigm(float x) { return 1.f / (1.f + expf(-x)); }

// ---------------- zero sync state ----------------
__global__ void k_zero(int* sync) {
    // sync: [0]=arrive, [1]=release, [2..129]=work counters (64 steps x 2)
    if (threadIdx.x < 132) sync[threadIdx.x] = 0;
}

// ---------------- grid barrier ----------------
__device__ __forceinline__ void grid_barrier(int* arrive, int* release, int idx, int tid) {
    __syncthreads();
    if (tid == 0) {
        __threadfence();  // agent-scope release: L2 writeback (cross-XCD visibility)
        int prev = __hip_atomic_fetch_add(arrive, 1, __ATOMIC_RELAXED, __HIP_MEMORY_SCOPE_AGENT);
        if (prev == idx * NBLK - 1) {
            __hip_atomic_store(release, idx, __ATOMIC_RELEASE, __HIP_MEMORY_SCOPE_AGENT);
        } else {
            while (__hip_atomic_load(release, __ATOMIC_RELAXED, __HIP_MEMORY_SCOPE_AGENT) < idx) {
                __builtin_amdgcn_s_sleep(2);
            }
        }
        __threadfence();  // agent-scope acquire: invalidate L1/L2
    }
    __syncthreads();
}

// ---------------- one GEMM unit: 128 rows x 128 cols x KS ----------------
// dst = partial slot base (layout [128][N]); acol0 = absolute X column of k-start.
__device__ void gemm_unit(const float* __restrict__ Xm, const float* __restrict__ WT,
                          float* __restrict__ dst, int N, int n0, int krow0, int acol0,
                          int KS, float (*As)[132], float (*Wsh)[132], int tid) {
    const int tm = tid >> 4;   // 0..15
    const int tn = tid & 15;   // 0..15
    float acc[8][8];
#pragma unroll
    for (int i = 0; i < 8; i++)
#pragma unroll
        for (int j = 0; j < 8; j++) acc[i][j] = 0.f;

    for (int ki = 0; ki < KS; ki += 32) {
        __syncthreads();
        {   // stage A: As[kk][m] = X[m][acol0+ki+kk]
            int m = tid >> 1;
            int c8 = (tid & 1) * 16;
            const float4* src = (const float4*)(Xm + (size_t)m * XW + acol0 + ki + c8);
#pragma unroll
            for (int j = 0; j < 4; j++) {
                float4 v = src[j];
                int kk = c8 + j * 4;
                As[kk + 0][m] = v.x; As[kk + 1][m] = v.y; As[kk + 2][m] = v.z; As[kk + 3][m] = v.w;
            }
        }
        {   // stage W: Wsh[kk][n] = WT[krow0+ki+kk][n0+n]
            int kk = tid >> 3;
            int c = (tid & 7) * 16;
            const float4* src = (const float4*)(WT + (size_t)(krow0 + ki + kk) * N + n0 + c);
            float4* d = (float4*)(&Wsh[kk][c]);
#pragma unroll
            for (int j = 0; j < 4; j++) d[j] = src[j];
        }
        __syncthreads();
#pragma unroll 4
        for (int kk = 0; kk < 32; kk++) {
            float a[8], w[8];
            *(float4*)&a[0] = *(const float4*)&As[kk][tm * 4];
            *(float4*)&a[4] = *(const float4*)&As[kk][64 + tm * 4];
            *(float4*)&w[0] = *(const float4*)&Wsh[kk][tn * 4];
            *(float4*)&w[4] = *(const float4*)&Wsh[kk][64 + tn * 4];
#pragma unroll
            for (int i = 0; i < 8; i++)
#pragma unroll
                for (int j = 0; j < 8; j++) acc[i][j] += a[i] * w[j];
        }
    }
    float* base = dst + n0;
#pragma unroll
    for (int i = 0; i < 8; i++) {
        int m = (i < 4) ? (tm * 4 + i) : (64 + tm * 4 + (i - 4));
        *(float4*)(base + (size_t)m * N + tn * 4) =
            make_float4(acc[i][0], acc[i][1], acc[i][2], acc[i][3]);
        *(float4*)(base + (size_t)m * N + 64 + tn * 4) =
            make_float4(acc[i][4], acc[i][5], acc[i][6], acc[i][7]);
    }
}

// ---------------- the persistent kernel ----------------
__global__ __launch_bounds__(NTHR, 1) void k_spinn(
    const float* __restrict__ buffers, const float* __restrict__ W_left,
    const float* __restrict__ b_left, const float* __restrict__ W_right,
    const float* __restrict__ W_track, const float* __restrict__ W_ih,
    const float* __restrict__ W_hh, const float* __restrict__ b_ih,
    const float* __restrict__ b_hh, const float* __restrict__ W_trans,
    const float* __restrict__ b_trans, float* __restrict__ out,
    float* __restrict__ W1T, float* __restrict__ W2T, float* __restrict__ b1,
    float* __restrict__ X, float* __restrict__ tc,
    float* __restrict__ g1part, float* __restrict__ g2part,
    float* __restrict__ stack, int* __restrict__ trans,
    int* __restrict__ sptr, int* __restrict__ blen, int* __restrict__ sync) {
    __shared__ float smem[8448];               // 33 KB, reused across phases
    __shared__ int s_u;
    float (*As)[132] = (float(*)[132])smem;
    float (*Wsh)[132] = (float(*)[132])(smem + 32 * 132);
    int* arrive = sync;
    int* release = sync + 1;
    int* ctr = sync + 2;

    const int bid = blockIdx.x, tid = threadIdx.x;
    int barid = 0;

    // ---- init: weight repack (all blocks, grid-strided) + state init (blocks<128) ----
    {
        const size_t n1 = 1792ull * 1024ull;
        const size_t n2 = 1280ull * 2560ull;
        const size_t total = n1 + n2 + 1024;
        for (size_t idx = (size_t)bid * NTHR + tid; idx < total; idx += (size_t)NBLK * NTHR) {
            if (idx < n1) {
                int k = (int)(idx >> 10), n = (int)(idx & 1023);
                W1T[idx] = (k < 1536) ? W_ih[(size_t)n * 1536 + k]
                                      : W_hh[(size_t)n * 256 + (k - 1536)];
            } else if (idx < n1 + n2) {
                size_t r = idx - n1;
                int k = (int)(r / 2560), n = (int)(r % 2560);
                float v;
                if (k < 512)       v = W_right[(size_t)n * 512 + k];
                else if (k < 1024) v = W_left [(size_t)n * 512 + (k - 512)];
                else               v = W_track[(size_t)n * 256 + (k - 1024)];
                W2T[r] = v;
            } else {
                int i = (int)(idx - n1 - n2);
                b1[i] = b_ih[i] + b_hh[i];
            }
        }
        if (bid < 128) {
            int b = bid;
            const float* b0 = buffers + (size_t)b * 40 * 1024;
            const float* btop = b0 + 39 * 1024;
            float* stk = stack + (size_t)b * CAP * 1024;
            for (int j = tid; j < 1024; j += 256) { stk[j] = b0[j]; stk[1024 + j] = b0[j]; }
            float* Xb = X + (size_t)b * XW;
            for (int j = tid; j < 512; j += 256) {
                Xb[j] = btop[j]; Xb[512 + j] = b0[j]; Xb[1024 + j] = b0[j];
            }
            Xb[1536 + tid] = 0.f;
            Xb[1792 + tid] = 0.f;
            tc[b * 256 + tid] = 0.f;
            if (tid == 0) { sptr[b] = 2; blen[b] = 40; }
        }
    }
    grid_barrier(arrive, release, ++barid, tid);

#pragma unroll 1
    for (int s = 0; s < 64; s++) {
        // ---------- Phase A: GEMM2a (160 units, K-chunk 128) + GEMM1 (224 units, K-chunk 64) ----------
        {
            int* c = &ctr[s * 2];
            for (;;) {
                __syncthreads();
                if (tid == 0) s_u = atomicAdd(c, 1);
                __syncthreads();
                int u = s_u;
                if (u >= 384) break;
                if (u < 160) {          // GEMM2a: s1h|s2h part, K=1024
                    int n0 = (u % 20) * 128, kc = u / 20;          // kc 0..7
                    gemm_unit(X, W2T, g2part + (size_t)kc * 327680, 2560,
                              n0, kc * 128, 512 + kc * 128, 128, As, Wsh, tid);
                } else {                // GEMM1: K=1792
                    int v = u - 160;
                    int n0 = (v & 7) * 128, kc = v >> 3;           // kc 0..27
                    gemm_unit(X, W1T, g1part + (size_t)kc * 131072, 1024,
                              n0, kc * 64, kc * 64, 64, As, Wsh, tid);
                }
            }
        }
        grid_barrier(arrive, release, ++barid, tid);

        // ---------- Phase B: gate sum + tracker cell + logits + argmax (blocks 0..127) ----------
        if (bid < 128) {
            int b = bid, t = tid;
            const float* gp = g1part + (size_t)b * 1024;
            float gi = b1[t], gf = b1[256 + t], gg = b1[512 + t], go = b1[768 + t];
#pragma unroll 7
            for (int kc = 0; kc < 28; kc++) {
                const float* p = gp + (size_t)kc * 131072;
                gi += p[t]; gf += p[256 + t]; gg += p[512 + t]; go += p[768 + t];
            }
            float tcv = tc[b * 256 + t];
            float tcn = sigm(gf) * tcv + sigm(gi) * tanhf(gg);
            float thn = sigm(go) * tanhf(tcn);
            tc[b * 256 + t] = tcn;
            X[(size_t)b * XW + 1792 + t] = thn;

            float* red = smem;   // [256][4]
            red[t * 4 + 0] = thn * W_trans[t];
            red[t * 4 + 1] = thn * W_trans[256 + t];
            red[t * 4 + 2] = thn * W_trans[512 + t];
            red[t * 4 + 3] = thn * W_trans[768 + t];
            __syncthreads();
            for (int off = 128; off > 0; off >>= 1) {
                if (t < off) {
                    red[t * 4 + 0] += red[(t + off) * 4 + 0];
                    red[t * 4 + 1] += red[(t + off) * 4 + 1];
                    red[t * 4 + 2] += red[(t + off) * 4 + 2];
                    red[t * 4 + 3] += red[(t + off) * 4 + 3];
                }
                __syncthreads();
            }
            if (t == 0) {
                int tr = 0; float best = -1e30f;
#pragma unroll
                for (int l = 0; l < 4; l++) {
                    float lg = red[l] + b_trans[l];
                    if (lg > best) { best = lg; tr = l; }    // first-max, matches jnp.argmax
                    out[(size_t)s * 512 + b * 4 + l] = lg;
                }
                trans[b] = tr;
            }
        }
        grid_barrier(arrive, release, ++barid, tid);

        // ---------- Phase C: th-GEMM (K=256, 160 units k=32) -> th partials in g1part ----------
        {
            int* c = &ctr[s * 2 + 1];
            for (;;) {
                __syncthreads();
                if (tid == 0) s_u = atomicAdd(c, 1);
                __syncthreads();
                int u = s_u;
                if (u >= 160) break;
                int n0 = (u % 20) * 128, kc = u / 20;              // kc 0..7
                gemm_unit(X, W2T, g1part + (size_t)kc * 327680, 2560,
                          n0, 1024 + kc * 32, 1792 + kc * 32, 32, As, Wsh, tid);
            }
        }
        grid_barrier(arrive, release, ++barid, tid);

        // ---------- Phase D: TreeLSTM node + stack update + next-X gather (blocks 0..127) ----------
        if (bid < 128) {
            int b = bid, t = tid;
            int tr = trans[b], sp = sptr[b], bl = blen[b];
            bool do_shift = (tr == 3) && (bl > 2);
            bool do_red   = (tr == 2) && (sp > 3);
            float* stk = stack + (size_t)b * CAP * 1024;
            float* nodeh = smem;
            float* nodec = smem + 512;

            if (do_red) {
                const float* s1 = stk + (size_t)(sp - 1) * 1024;
                const float* s2 = stk + (size_t)(sp - 2) * 1024;
                for (int j = t; j < 512; j += 256) {
                    float a = b_left[j], i_ = b_left[512 + j], f1 = b_left[1024 + j],
                          f2 = b_left[1536 + j], o = b_left[2048 + j];
#pragma unroll
                    for (int kc = 0; kc < 8; kc++) {       // GEMM2a partials
                        const float* p = g2part + (size_t)kc * 327680 + (size_t)b * 2560;
                        a += p[j]; i_ += p[512 + j]; f1 += p[1024 + j];
                        f2 += p[1536 + j]; o += p[2048 + j];
                    }
#pragma unroll
                    for (int kc = 0; kc < 8; kc++) {       // th partials (aliased in g1part)
                        const float* p = g1part + (size_t)kc * 327680 + (size_t)b * 2560;
                        a += p[j]; i_ += p[512 + j]; f1 += p[1024 + j];
                        f2 += p[1536 + j]; o += p[2048 + j];
                    }
                    float c = tanhf(a) * sigm(i_) + sigm(f1) * s2[512 + j] + sigm(f2) * s1[512 + j];
                    float h = sigm(o) * tanhf(c);
                    nodeh[j] = h; nodec[j] = c;
                }
            }
            __syncthreads();
            if (do_red) {
                float* dst = stk + (size_t)(sp - 2) * 1024;
                for (int j = t; j < 512; j += 256) { dst[j] = nodeh[j]; dst[512 + j] = nodec[j]; }
            }
            if (do_shift) {
                const float* bt = buffers + ((size_t)b * 40 + (bl - 1)) * 1024;
                float* dst = stk + (size_t)sp * 1024;
                for (int j = t; j < 1024; j += 256) dst[j] = bt[j];
            }
            int spn = sp + (do_shift ? 1 : 0) - (do_red ? 1 : 0);
            int bln = bl - (do_shift ? 1 : 0);
            if (t == 0) { sptr[b] = spn; blen[b] = bln; }
            __syncthreads();

            float* Xb = X + (size_t)b * XW;
            const float* btn = buffers + ((size_t)b * 40 + (bln - 1)) * 1024;
            for (int j = t; j < 512; j += 256) Xb[j] = btn[j];
            if (do_red) {
                for (int j = t; j < 512; j += 256) Xb[512 + j] = nodeh[j];
            } else if (do_shift) {
                const float* src = buffers + ((size_t)b * 40 + (bl - 1)) * 1024;
                for (int j = t; j < 512; j += 256) Xb[512 + j] = src[j];
            } else {
                const float* src = stk + (size_t)(sp - 1) * 1024;
                for (int j = t; j < 512; j += 256) Xb[512 + j] = src[j];
            }
            {
                const float* src = stk + (size_t)(spn - 2) * 1024;
                for (int j = t; j < 512; j += 256) Xb[1024 + j] = src[j];
            }
            Xb[1536 + t] = Xb[1792 + t];
        }
        grid_barrier(arrive, release, ++barid, tid);
    }
}

// ---------------- host ----------------
extern "C" void kernel_launch(void* const* d_in, const int* in_sizes, int n_in,
                              void* d_out, int out_size, void* d_ws, size_t ws_size,
                              hipStream_t stream) {
    const float* buffers = (const float*)d_in[0];
    const float* W_left  = (const float*)d_in[1];
    const float* b_left  = (const float*)d_in[2];
    const float* W_right = (const float*)d_in[3];
    const float* W_track = (const float*)d_in[4];
    const float* W_ih    = (const float*)d_in[5];
    const float* W_hh    = (const float*)d_in[6];
    const float* b_ih    = (const float*)d_in[7];
    const float* b_hh    = (const float*)d_in[8];
    const float* W_trans = (const float*)d_in[9];
    const float* b_trans = (const float*)d_in[10];
    float* out = (float*)d_out;

    float* ws = (float*)d_ws;
    size_t off = 0;
    float* W1T    = ws + off; off += 1792ull * 1024;                 // 1,835,008
    float* W2T    = ws + off; off += 1280ull * 2560;                 // 3,276,800
    float* b1     = ws + off; off += 1024;
    float* X      = ws + off; off += (size_t)B_ * XW;                // 262,144
    float* tc     = ws + off; off += (size_t)B_ * 256;
    float* g1part = ws + off; off += 28ull * 128 * 1024;             // 3,670,016 (aliases th partials 8x327680)
    float* g2part = ws + off; off += 8ull * 128 * 2560;              // 2,621,440
    float* stack  = ws + off; off += (size_t)B_ * CAP * 1024;        // 5,505,024
    int*   trans  = (int*)(ws + off); off += 128;
    int*   sptr   = (int*)(ws + off); off += 128;
    int*   blen   = (int*)(ws + off); off += 128;
    int*   sync   = (int*)(ws + off); off += 160;                    // arrive, release, ctr[128]

    k_zero<<<1, 256, 0, stream>>>(sync);
    k_spinn<<<NBLK, NTHR, 0, stream>>>(buffers, W_left, b_left, W_right, W_track,
                                       W_ih, W_hh, b_ih, b_hh, W_trans, b_trans, out,
                                       W1T, W2T, b1, X, tc, g1part, g2part, stack,
                                       trans, sptr, blen, sync);
    (void)in_sizes; (void)n_in; (void)out_size; (void)ws_size;
}

// Round 3
// 6763.799 us; speedup vs baseline: 1.2453x; 1.2453x over previous
//
#include <hip/hip_runtime.h>
#include <math.h>

// SPINN forward, fp32, single persistent kernel, fence-free cross-XCD coherence:
//  - weights: plain cached loads, stay L2-resident all 64 steps (never invalidated)
//  - partials/X (cross-XCD producer-consumer): sc0/sc1 per-access coherent via
//    __hip_atomic_{load,store}(RELAXED, AGENT) -> no cache-wide fences needed
//  - grid barrier: 2-level arrive counters + release word, zero fences
// Phases per step: A = GEMM1 + GEMM2a | B = cell/logits/argmax | C = th-GEMM | D = node/stack/gather

#define B_ 128
#define CAP 42
#define XW 2048   // X row: [buf_h 0:512 | s1_h 512:1024 | s2_h 1024:1536 | th_old 1536:1792 | th_new 1792:2048]
#define NBLK 512
#define NTHR 256

__device__ __forceinline__ float sigm(float x) { return 1.f / (1.f + expf(-x)); }

// coherent (device-scope, L1/L2-bypassing) scalar access
__device__ __forceinline__ float cload(const float* p) {
    return __hip_atomic_load(p, __ATOMIC_RELAXED, __HIP_MEMORY_SCOPE_AGENT);
}
__device__ __forceinline__ void cstore(float* p, float v) {
    __hip_atomic_store(p, v, __ATOMIC_RELAXED, __HIP_MEMORY_SCOPE_AGENT);
}

// sync layout (ints): [r*256] 8 leaf counters, [2048] root, [2049] release, [2056..2183] steal ctrs
#define SYNC_INTS 4096

__global__ void k_zero(int* sync) {
    for (int i = threadIdx.x; i < SYNC_INTS; i += 256) sync[i] = 0;
}

__device__ __forceinline__ void grid_barrier(int* sync, int idx, int tid, int bid) {
    __syncthreads();   // drains each wave's outstanding stores (waitcnt before s_barrier)
    if (tid == 0) {
        int* leaf = sync + (bid & 7) * 256;
        int* root = sync + 2048;
        int* release = sync + 2049;
        int prev = __hip_atomic_fetch_add(leaf, 1, __ATOMIC_RELAXED, __HIP_MEMORY_SCOPE_AGENT);
        if (prev == idx * (NBLK / 8) - 1) {
            int r = __hip_atomic_fetch_add(root, 1, __ATOMIC_RELAXED, __HIP_MEMORY_SCOPE_AGENT);
            if (r == idx * 8 - 1) {
                __hip_atomic_store(release, idx, __ATOMIC_RELAXED, __HIP_MEMORY_SCOPE_AGENT);
            }
        }
        while (__hip_atomic_load(sync + 2049, __ATOMIC_RELAXED, __HIP_MEMORY_SCOPE_AGENT) < idx) {
            __builtin_amdgcn_s_sleep(4);
        }
    }
    __syncthreads();
}

// ---------------- one GEMM unit: 128 rows x 128 cols x KS ----------------
// X read coherently (scalar), W read cached (float4), partials stored coherently (scalar).
__device__ void gemm_unit(const float* __restrict__ Xm, const float* __restrict__ WT,
                          float* __restrict__ dst, int N, int n0, int krow0, int acol0,
                          int KS, float (*As)[132], float (*Wsh)[132], int tid) {
    const int tm = tid >> 4;   // 0..15
    const int tn = tid & 15;   // 0..15
    float acc[8][8];
#pragma unroll
    for (int i = 0; i < 8; i++)
#pragma unroll
        for (int j = 0; j < 8; j++) acc[i][j] = 0.f;

    for (int ki = 0; ki < KS; ki += 32) {
        __syncthreads();
        {   // stage A (coherent): As[kk][m] = X[m][acol0+ki+kk]
            int m = tid >> 1;
            int c8 = (tid & 1) * 16;
            const float* src = Xm + (size_t)m * XW + acol0 + ki + c8;
#pragma unroll
            for (int j = 0; j < 16; j++) As[c8 + j][m] = cload(src + j);
        }
        {   // stage W (cached): Wsh[kk][n] = WT[krow0+ki+kk][n0+n]
            int kk = tid >> 3;
            int c = (tid & 7) * 16;
            const float4* src = (const float4*)(WT + (size_t)(krow0 + ki + kk) * N + n0 + c);
            float4* d = (float4*)(&Wsh[kk][c]);
#pragma unroll
            for (int j = 0; j < 4; j++) d[j] = src[j];
        }
        __syncthreads();
#pragma unroll 4
        for (int kk = 0; kk < 32; kk++) {
            float a[8], w[8];
            *(float4*)&a[0] = *(const float4*)&As[kk][tm * 4];
            *(float4*)&a[4] = *(const float4*)&As[kk][64 + tm * 4];
            *(float4*)&w[0] = *(const float4*)&Wsh[kk][tn * 4];
            *(float4*)&w[4] = *(const float4*)&Wsh[kk][64 + tn * 4];
#pragma unroll
            for (int i = 0; i < 8; i++)
#pragma unroll
                for (int j = 0; j < 8; j++) acc[i][j] += a[i] * w[j];
        }
    }
    float* base = dst + n0;
#pragma unroll
    for (int i = 0; i < 8; i++) {
        int m = (i < 4) ? (tm * 4 + i) : (64 + tm * 4 + (i - 4));
        float* row = base + (size_t)m * N;
#pragma unroll
        for (int j = 0; j < 4; j++) cstore(row + tn * 4 + j, acc[i][j]);
#pragma unroll
        for (int j = 0; j < 4; j++) cstore(row + 64 + tn * 4 + j, acc[i][4 + j]);
    }
}

// ---------------- the persistent kernel ----------------
__global__ __launch_bounds__(NTHR, 2) void k_spinn(
    const float* __restrict__ buffers, const float* __restrict__ W_left,
    const float* __restrict__ b_left, const float* __restrict__ W_right,
    const float* __restrict__ W_track, const float* __restrict__ W_ih,
    const float* __restrict__ W_hh, const float* __restrict__ b_ih,
    const float* __restrict__ b_hh, const float* __restrict__ W_trans,
    const float* __restrict__ b_trans, float* __restrict__ out,
    float* __restrict__ W1T, float* __restrict__ W2T, float* __restrict__ b1,
    float* __restrict__ X, float* __restrict__ tc,
    float* __restrict__ g1part, float* __restrict__ g2part,
    float* __restrict__ stack, int* __restrict__ trans,
    int* __restrict__ sptr, int* __restrict__ blen, int* __restrict__ sync) {
    __shared__ float smem[8448];               // 33 KB, reused across phases
    __shared__ int s_u;
    float (*As)[132] = (float(*)[132])smem;
    float (*Wsh)[132] = (float(*)[132])(smem + 32 * 132);
    int* ctr = sync + 2056;

    const int bid = blockIdx.x, tid = threadIdx.x;
    int barid = 0;

    // ---- init: weight repack (grid-strided, plain cached stores) + state init ----
    {
        const size_t n1 = 1792ull * 1024ull;
        const size_t n2 = 1280ull * 2560ull;
        const size_t total = n1 + n2 + 1024;
        for (size_t idx = (size_t)bid * NTHR + tid; idx < total; idx += (size_t)NBLK * NTHR) {
            if (idx < n1) {
                int k = (int)(idx >> 10), n = (int)(idx & 1023);
                W1T[idx] = (k < 1536) ? W_ih[(size_t)n * 1536 + k]
                                      : W_hh[(size_t)n * 256 + (k - 1536)];
            } else if (idx < n1 + n2) {
                size_t r = idx - n1;
                int k = (int)(r / 2560), n = (int)(r % 2560);
                float v;
                if (k < 512)       v = W_right[(size_t)n * 512 + k];
                else if (k < 1024) v = W_left [(size_t)n * 512 + (k - 512)];
                else               v = W_track[(size_t)n * 256 + (k - 1024)];
                W2T[r] = v;
            } else {
                int i = (int)(idx - n1 - n2);
                b1[i] = b_ih[i] + b_hh[i];
            }
        }
        if (bid < 128) {
            int b = bid;
            const float* b0 = buffers + (size_t)b * 40 * 1024;
            const float* btop = b0 + 39 * 1024;
            float* stk = stack + (size_t)b * CAP * 1024;
            for (int j = tid; j < 1024; j += 256) { stk[j] = b0[j]; stk[1024 + j] = b0[j]; }
            float* Xb = X + (size_t)b * XW;
            for (int j = tid; j < 512; j += 256) {
                Xb[j] = btop[j]; Xb[512 + j] = b0[j]; Xb[1024 + j] = b0[j];
            }
            Xb[1536 + tid] = 0.f;
            Xb[1792 + tid] = 0.f;
            tc[b * 256 + tid] = 0.f;
            if (tid == 0) { sptr[b] = 2; blen[b] = 40; }
        }
    }
    // one-time publish of repacked weights + init state: L2 writeback (no invalidate)
    __syncthreads();
    if (tid == 0) __builtin_amdgcn_fence(__ATOMIC_RELEASE, "agent");
    grid_barrier(sync, ++barid, tid, bid);

#pragma unroll 1
    for (int s = 0; s < 64; s++) {
        // ---------- Phase A: GEMM2a (160 units, K=128) + GEMM1 (224 units, K=64) ----------
        {
            int* c = &ctr[s * 2];
            for (;;) {
                __syncthreads();
                if (tid == 0) s_u = atomicAdd(c, 1);
                __syncthreads();
                int u = s_u;
                if (u >= 384) break;
                if (u < 160) {          // GEMM2a: s1h|s2h part, K=1024
                    int n0 = (u % 20) * 128, kc = u / 20;          // kc 0..7
                    gemm_unit(X, W2T, g2part + (size_t)kc * 327680, 2560,
                              n0, kc * 128, 512 + kc * 128, 128, As, Wsh, tid);
                } else {                // GEMM1: K=1792
                    int v = u - 160;
                    int n0 = (v & 7) * 128, kc = v >> 3;           // kc 0..27
                    gemm_unit(X, W1T, g1part + (size_t)kc * 131072, 1024,
                              n0, kc * 64, kc * 64, 64, As, Wsh, tid);
                }
            }
        }
        grid_barrier(sync, ++barid, tid, bid);

        // ---------- Phase B: gate sum + tracker cell + logits + argmax (blocks 0..127) ----------
        if (bid < 128) {
            int b = bid, t = tid;
            const float* gp = g1part + (size_t)b * 1024;
            float gi = b1[t], gf = b1[256 + t], gg = b1[512 + t], go = b1[768 + t];
#pragma unroll 7
            for (int kc = 0; kc < 28; kc++) {
                const float* p = gp + (size_t)kc * 131072;
                gi += cload(p + t); gf += cload(p + 256 + t);
                gg += cload(p + 512 + t); go += cload(p + 768 + t);
            }
            float tcv = tc[b * 256 + t];
            float tcn = sigm(gf) * tcv + sigm(gi) * tanhf(gg);
            float thn = sigm(go) * tanhf(tcn);
            tc[b * 256 + t] = tcn;
            cstore(X + (size_t)b * XW + 1792 + t, thn);

            float* red = smem;   // [256][4]
            red[t * 4 + 0] = thn * W_trans[t];
            red[t * 4 + 1] = thn * W_trans[256 + t];
            red[t * 4 + 2] = thn * W_trans[512 + t];
            red[t * 4 + 3] = thn * W_trans[768 + t];
            __syncthreads();
            for (int off = 128; off > 0; off >>= 1) {
                if (t < off) {
                    red[t * 4 + 0] += red[(t + off) * 4 + 0];
                    red[t * 4 + 1] += red[(t + off) * 4 + 1];
                    red[t * 4 + 2] += red[(t + off) * 4 + 2];
                    red[t * 4 + 3] += red[(t + off) * 4 + 3];
                }
                __syncthreads();
            }
            if (t == 0) {
                int tr = 0; float best = -1e30f;
#pragma unroll
                for (int l = 0; l < 4; l++) {
                    float lg = red[l] + b_trans[l];
                    if (lg > best) { best = lg; tr = l; }    // first-max, matches jnp.argmax
                    out[(size_t)s * 512 + b * 4 + l] = lg;
                }
                trans[b] = tr;
            }
        }
        grid_barrier(sync, ++barid, tid, bid);

        // ---------- Phase C: th-GEMM (K=256, 160 units k=32) -> th partials in g1part ----------
        {
            int* c = &ctr[s * 2 + 1];
            for (;;) {
                __syncthreads();
                if (tid == 0) s_u = atomicAdd(c, 1);
                __syncthreads();
                int u = s_u;
                if (u >= 160) break;
                int n0 = (u % 20) * 128, kc = u / 20;              // kc 0..7
                gemm_unit(X, W2T, g1part + (size_t)kc * 327680, 2560,
                          n0, 1024 + kc * 32, 1792 + kc * 32, 32, As, Wsh, tid);
            }
        }
        grid_barrier(sync, ++barid, tid, bid);

        // ---------- Phase D: TreeLSTM node + stack update + next-X gather (blocks 0..127) ----------
        if (bid < 128) {
            int b = bid, t = tid;
            int tr = trans[b], sp = sptr[b], bl = blen[b];
            bool do_shift = (tr == 3) && (bl > 2);
            bool do_red   = (tr == 2) && (sp > 3);
            float* stk = stack + (size_t)b * CAP * 1024;   // stack/tc/trans: same-block only -> cached
            float* nodeh = smem;
            float* nodec = smem + 512;

            if (do_red) {
                const float* s1 = stk + (size_t)(sp - 1) * 1024;
                const float* s2 = stk + (size_t)(sp - 2) * 1024;
                for (int j = t; j < 512; j += 256) {
                    float a = b_left[j], i_ = b_left[512 + j], f1 = b_left[1024 + j],
                          f2 = b_left[1536 + j], o = b_left[2048 + j];
#pragma unroll
                    for (int kc = 0; kc < 8; kc++) {       // GEMM2a partials
                        const float* p = g2part + (size_t)kc * 327680 + (size_t)b * 2560;
                        a += cload(p + j); i_ += cload(p + 512 + j); f1 += cload(p + 1024 + j);
                        f2 += cload(p + 1536 + j); o += cload(p + 2048 + j);
                    }
#pragma unroll
                    for (int kc = 0; kc < 8; kc++) {       // th partials (aliased in g1part)
                        const float* p = g1part + (size_t)kc * 327680 + (size_t)b * 2560;
                        a += cload(p + j); i_ += cload(p + 512 + j); f1 += cload(p + 1024 + j);
                        f2 += cload(p + 1536 + j); o += cload(p + 2048 + j);
                    }
                    float c = tanhf(a) * sigm(i_) + sigm(f1) * s2[512 + j] + sigm(f2) * s1[512 + j];
                    float h = sigm(o) * tanhf(c);
                    nodeh[j] = h; nodec[j] = c;
                }
            }
            __syncthreads();
            if (do_red) {
                float* dst = stk + (size_t)(sp - 2) * 1024;
                for (int j = t; j < 512; j += 256) { dst[j] = nodeh[j]; dst[512 + j] = nodec[j]; }
            }
            if (do_shift) {
                const float* bt = buffers + ((size_t)b * 40 + (bl - 1)) * 1024;
                float* dst = stk + (size_t)sp * 1024;
                for (int j = t; j < 1024; j += 256) dst[j] = bt[j];
            }
            int spn = sp + (do_shift ? 1 : 0) - (do_red ? 1 : 0);
            int bln = bl - (do_shift ? 1 : 0);
            if (t == 0) { sptr[b] = spn; blen[b] = bln; }
            __syncthreads();

            float* Xb = X + (size_t)b * XW;                // X: cross-XCD -> coherent stores
            const float* btn = buffers + ((size_t)b * 40 + (bln - 1)) * 1024;
            for (int j = t; j < 512; j += 256) cstore(Xb + j, btn[j]);
            if (do_red) {
                for (int j = t; j < 512; j += 256) cstore(Xb + 512 + j, nodeh[j]);
            } else if (do_shift) {
                const float* src = buffers + ((size_t)b * 40 + (bl - 1)) * 1024;
                for (int j = t; j < 512; j += 256) cstore(Xb + 512 + j, src[j]);
            } else {
                const float* src = stk + (size_t)(sp - 1) * 1024;
                for (int j = t; j < 512; j += 256) cstore(Xb + 512 + j, src[j]);
            }
            {
                const float* src = stk + (size_t)(spn - 2) * 1024;
                for (int j = t; j < 512; j += 256) cstore(Xb + 1024 + j, src[j]);
            }
            cstore(Xb + 1536 + t, cload(Xb + 1792 + t));   // th_old <- th_new
        }
        grid_barrier(sync, ++barid, tid, bid);
    }
}

// ---------------- host ----------------
extern "C" void kernel_launch(void* const* d_in, const int* in_sizes, int n_in,
                              void* d_out, int out_size, void* d_ws, size_t ws_size,
                              hipStream_t stream) {
    const float* buffers = (const float*)d_in[0];
    const float* W_left  = (const float*)d_in[1];
    const float* b_left  = (const float*)d_in[2];
    const float* W_right = (const float*)d_in[3];
    const float* W_track = (const float*)d_in[4];
    const float* W_ih    = (const float*)d_in[5];
    const float* W_hh    = (const float*)d_in[6];
    const float* b_ih    = (const float*)d_in[7];
    const float* b_hh    = (const float*)d_in[8];
    const float* W_trans = (const float*)d_in[9];
    const float* b_trans = (const float*)d_in[10];
    float* out = (float*)d_out;

    float* ws = (float*)d_ws;
    size_t off = 0;
    float* W1T    = ws + off; off += 1792ull * 1024;                 // 1,835,008
    float* W2T    = ws + off; off += 1280ull * 2560;                 // 3,276,800
    float* b1     = ws + off; off += 1024;
    float* X      = ws + off; off += (size_t)B_ * XW;                // 262,144
    float* tc     = ws + off; off += (size_t)B_ * 256;
    float* g1part = ws + off; off += 28ull * 128 * 1024;             // 3,670,016 (th partials aliased: 8x327680)
    float* g2part = ws + off; off += 8ull * 128 * 2560;              // 2,621,440
    float* stack  = ws + off; off += (size_t)B_ * CAP * 1024;        // 5,505,024
    int*   trans  = (int*)(ws + off); off += 128;
    int*   sptr   = (int*)(ws + off); off += 128;
    int*   blen   = (int*)(ws + off); off += 128;
    int*   sync   = (int*)(ws + off); off += SYNC_INTS;

    k_zero<<<1, 256, 0, stream>>>(sync);
    k_spinn<<<NBLK, NTHR, 0, stream>>>(buffers, W_left, b_left, W_right, W_track,
                                       W_ih, W_hh, b_ih, b_hh, W_trans, b_trans, out,
                                       W1T, W2T, b1, X, tc, g1part, g2part, stack,
                                       trans, sptr, blen, sync);
    (void)in_sizes; (void)n_in; (void)out_size; (void)ws_size;
}